// Round 1
// baseline (106.823 us; speedup 1.0000x reference)
//
#include <hip/hip_runtime.h>

// AdditiveSelfAttentionLayer: B=4, N=1024, D=64, fp32
// out[b,i,d] = sum_j softmax_j( sum_d' tanh(x[b,i,d']+x[b,j,d']) ) * x[b,j,d]

#define NB 4
#define NN 1024
#define ND 64
#define TJ 128            // j-rows staged per LDS tile
#define NWAVES 4          // rows (waves) per workgroup
#define NTILES (NN / TJ)

#if __has_builtin(__builtin_amdgcn_exp2f)
#define EXP2F(x) __builtin_amdgcn_exp2f(x)
#else
#define EXP2F(x) exp2f(x)
#endif
#if __has_builtin(__builtin_amdgcn_rcpf)
#define RCPF(x) __builtin_amdgcn_rcpf(x)
#else
#define RCPF(x) (1.0f / (x))
#endif

static constexpr float C_SCALE = 2.8853900817779268f;   // 2*log2(e)
static constexpr float INV_C   = 0.34657359027997264f;  // 1/C_SCALE

__global__ __launch_bounds__(256) void addattn_kernel(const float* __restrict__ x,
                                                      float* __restrict__ out) {
    // xj tile, pre-scaled by C_SCALE, XOR-swizzled at float4 granularity
    __shared__ float xj_lds[TJ * ND];      // 32 KB
    __shared__ float xi_lds[NWAVES * ND];  // 1 KB, pre-scaled

    const int tid   = threadIdx.x;
    const int lane  = tid & 63;
    const int wave  = tid >> 6;
    const int wg    = blockIdx.x;
    const int b     = wg >> 8;              // 256 WGs per batch
    const int ibase = (wg & 255) * NWAVES;

    const float* xb = x + (size_t)b * NN * ND;

    // stage the 4 xi rows for this WG (256 consecutive floats)
    xi_lds[tid] = xb[(size_t)ibase * ND + tid] * C_SCALE;

    float accs[ND];
    #pragma unroll
    for (int k = 0; k < ND; ++k) accs[k] = 0.0f;
    float denom = 0.0f;

    for (int t = 0; t < NTILES; ++t) {
        __syncthreads();   // protect LDS from previous iteration's readers (also publishes xi at t=0)
        {
            // stage tile t: TJ*ND floats = 2048 float4 over 256 threads
            const float4* src = (const float4*)(xb + (size_t)t * TJ * ND);
            #pragma unroll
            for (int it = 0; it < (TJ * ND / 4) / 256; ++it) {
                int idx = it * 256 + tid;
                int j   = idx >> 4;         // 16 float4 per row
                int d4  = idx & 15;
                float4 v = src[idx];
                v.x *= C_SCALE; v.y *= C_SCALE; v.z *= C_SCALE; v.w *= C_SCALE;
                int w = j * ND + ((d4 ^ (j & 15)) << 2);
                *(float4*)&xj_lds[w] = v;
            }
        }
        __syncthreads();

        #pragma unroll
        for (int jb = 0; jb < TJ / 64; ++jb) {
            const int jloc   = jb * 64 + lane;
            const int xorkey = jloc & 15;
            const int jbase  = jloc * ND;
            float xjs[ND];
            float rs0 = 0.f, rs1 = 0.f, rs2 = 0.f, rs3 = 0.f;
            #pragma unroll
            for (int d4 = 0; d4 < 16; ++d4) {
                float4 xj4 = *(const float4*)&xj_lds[jbase + ((d4 ^ xorkey) << 2)];
                float4 xi4 = *(const float4*)&xi_lds[wave * ND + d4 * 4];
                xjs[d4 * 4 + 0] = xj4.x; xjs[d4 * 4 + 1] = xj4.y;
                xjs[d4 * 4 + 2] = xj4.z; xjs[d4 * 4 + 3] = xj4.w;
                // r = 1/(1+e^{2s}); tanh = 1-2r; accumulate r only
                rs0 += RCPF(EXP2F(xi4.x + xj4.x) + 1.0f);
                rs1 += RCPF(EXP2F(xi4.y + xj4.y) + 1.0f);
                rs2 += RCPF(EXP2F(xi4.z + xj4.z) + 1.0f);
                rs3 += RCPF(EXP2F(xi4.w + xj4.w) + 1.0f);
            }
            float rsum = (rs0 + rs1) + (rs2 + rs3);
            // e - 64 = -2*rsum ; w = exp(e-64) = exp2(-C_SCALE*rsum)  (always <= 1)
            float wgt = EXP2F(-C_SCALE * rsum);
            denom += wgt;
            #pragma unroll
            for (int k = 0; k < ND; ++k) accs[k] = fmaf(wgt, xjs[k], accs[k]);
        }
    }

    // Cross-lane transpose-reduction: out[d] = sum over lanes of accs[d].
    // Register-halving butterfly; at step s select by lane bit (5-s), partner
    // mask = 32>>s. Final: accs[0] on lane l holds out[d=l].
    #pragma unroll
    for (int s = 0; s < 6; ++s) {
        const int half = 32 >> s;
        const int sel  = (lane >> (5 - s)) & 1;
        #pragma unroll
        for (int k = 0; k < half; ++k) {
            float keep = sel ? accs[k + half] : accs[k];
            float send = sel ? accs[k] : accs[k + half];
            float recv = __shfl_xor(send, half, 64);
            accs[k] = keep + recv;
        }
    }
    #pragma unroll
    for (int s = 0; s < 6; ++s) denom += __shfl_xor(denom, 1 << s, 64);

    const int i = ibase + wave;
    out[((size_t)b * NN + i) * ND + lane] = accs[0] * INV_C / denom;
}

extern "C" void kernel_launch(void* const* d_in, const int* in_sizes, int n_in,
                              void* d_out, int out_size, void* d_ws, size_t ws_size,
                              hipStream_t stream) {
    const float* x = (const float*)d_in[0];
    float* out = (float*)d_out;
    dim3 grid(NB * (NN / NWAVES));   // 1024 workgroups
    dim3 block(256);
    addattn_kernel<<<grid, block, 0, stream>>>(x, out);
}

// Round 2
// 74.983 us; speedup vs baseline: 1.4246x; 1.4246x over previous
//
#include <hip/hip_runtime.h>

// AdditiveSelfAttentionLayer: B=4, N=1024, D=64, fp32
// out[b,i,d] = sum_j softmax_j( sum_d' tanh(x[b,i,d']+x[b,j,d']) ) * x[b,j,d]
//
// Key identities:
//   tanh(s) = 1 - 2/(1+e^{2s});  sum_d tanh = 64 - 2*rsum, rsum = sum_d 1/(1+e^{2s})
//   e^{2s} = E_i[d]*E_j[d],  E = exp2(C*x), C = 2*log2(e)   (precomputed once)
//   softmax with fixed shift 64:  w_j = exp(e_j - 64) = exp2(-C*rsum_j)

#define NB 4
#define NN 1024
#define ND 64
#define TJ 64             // j-rows per LDS tile (= 64 lanes, lane = local j)
#define NWAVES 4          // one i-row per wave
#define NTILES (NN / TJ)  // 16

#if __has_builtin(__builtin_amdgcn_exp2f)
#define EXP2F(x) __builtin_amdgcn_exp2f(x)
#else
#define EXP2F(x) exp2f(x)
#endif
#if __has_builtin(__builtin_amdgcn_rcpf)
#define RCPF(x) __builtin_amdgcn_rcpf(x)
#else
#define RCPF(x) (1.0f / (x))
#endif

static constexpr float C_SCALE = 2.8853900817779268f;   // 2*log2(e)

__device__ __forceinline__ float readlane_f(float v, int l) {
    return __uint_as_float(__builtin_amdgcn_readlane(__float_as_uint(v), l));
}

// prep: E[i] = exp2(C * x[i]) for all B*N*D elements (float4-vectorized)
__global__ __launch_bounds__(256) void prep_kernel(const float* __restrict__ x,
                                                   float* __restrict__ E) {
    int idx = blockIdx.x * 256 + threadIdx.x;
    float4 v = ((const float4*)x)[idx];
    float4 e;
    e.x = EXP2F(C_SCALE * v.x);
    e.y = EXP2F(C_SCALE * v.y);
    e.z = EXP2F(C_SCALE * v.z);
    e.w = EXP2F(C_SCALE * v.w);
    ((float4*)E)[idx] = e;
}

template <bool HAS_E>
__global__ __launch_bounds__(256) void addattn_kernel(const float* __restrict__ x,
                                                      const float* __restrict__ E,
                                                      float* __restrict__ out) {
    __shared__ float x_lds[TJ * ND];        // 16 KB, linear (PV reads coalesced)
    __shared__ float E_lds[TJ * ND];        // 16 KB, XOR-swizzled at float4 grain
    __shared__ float Ei_lds[NWAVES * ND];   // 1 KB

    const int tid   = threadIdx.x;
    const int lane  = tid & 63;
    const int wave  = tid >> 6;
    const int wg    = blockIdx.x;
    const int b     = wg >> 8;              // 256 WGs per batch
    const int ibase = (wg & 255) * NWAVES;

    const float* xb = x + (size_t)b * NN * ND;
    const float* Eb = E + (size_t)b * NN * ND;

    // E for this WG's 4 i-rows (256 consecutive elements)
    Ei_lds[tid] = EXP2F(C_SCALE * xb[(size_t)ibase * ND + tid]);

    float acc    = 0.0f;   // out[i, d=lane] numerator
    float denomp = 0.0f;   // per-lane partial softmax denominator

    for (int t = 0; t < NTILES; ++t) {
        __syncthreads();   // protect LDS from previous tile's readers (publishes Ei at t=0)
        {
            const float4* srcx = (const float4*)(xb + (size_t)t * TJ * ND);
            const float4* srcE = (const float4*)(Eb + (size_t)t * TJ * ND);
            #pragma unroll
            for (int it = 0; it < (TJ * ND / 4) / 256; ++it) {   // 4 iters
                int idx = it * 256 + tid;
                int j   = idx >> 4;         // 16 float4 per row
                int d4  = idx & 15;
                float4 xv = srcx[idx];
                ((float4*)x_lds)[idx] = xv;              // linear
                float4 ev;
                if (HAS_E) {
                    ev = srcE[idx];
                } else {
                    ev.x = EXP2F(C_SCALE * xv.x);
                    ev.y = EXP2F(C_SCALE * xv.y);
                    ev.z = EXP2F(C_SCALE * xv.z);
                    ev.w = EXP2F(C_SCALE * xv.w);
                }
                *(float4*)&E_lds[j * ND + ((d4 ^ (j & 15)) << 2)] = ev;  // swizzled
            }
        }
        __syncthreads();

        // ---- tanh phase: lane = local j; in-lane accumulate over d ----
        const int xorkey = lane & 15;
        const float* Eirow = &Ei_lds[wave * ND];
        float rs0 = 0.f, rs1 = 0.f, rs2 = 0.f, rs3 = 0.f;
        #pragma unroll
        for (int d4 = 0; d4 < 16; ++d4) {
            float4 ej = *(const float4*)&E_lds[lane * ND + ((d4 ^ xorkey) << 2)];
            float4 ei = *(const float4*)&Eirow[d4 * 4];     // same-addr broadcast
            rs0 += RCPF(fmaf(ei.x, ej.x, 1.0f));
            rs1 += RCPF(fmaf(ei.y, ej.y, 1.0f));
            rs2 += RCPF(fmaf(ei.z, ej.z, 1.0f));
            rs3 += RCPF(fmaf(ei.w, ej.w, 1.0f));
        }
        float rsum = (rs0 + rs1) + (rs2 + rs3);
        // e - 64 = -2*rsum ; w = exp2(-C*rsum) <= 1
        float w = EXP2F(-C_SCALE * rsum);
        denomp += w;

        // ---- PV phase: acc[d=lane] += sum_j w_j * x[j][lane] ----
        // readlane broadcast (j is a compile-time constant per unrolled iter);
        // x_lds read coalesced: banks = lane%32, 2-way alias = free.
        #pragma unroll
        for (int j = 0; j < TJ; ++j) {
            float wj = readlane_f(w, j);
            acc = fmaf(wj, x_lds[j * ND + lane], acc);
        }
    }

    // reduce denominator across lanes (each lane held w for its j's)
    #pragma unroll
    for (int s = 0; s < 6; ++s) denomp += __shfl_xor(denomp, 1 << s, 64);

    const int i = ibase + wave;
    out[((size_t)b * NN + i) * ND + lane] = acc * RCPF(denomp);
}

extern "C" void kernel_launch(void* const* d_in, const int* in_sizes, int n_in,
                              void* d_out, int out_size, void* d_ws, size_t ws_size,
                              hipStream_t stream) {
    const float* x = (const float*)d_in[0];
    float* out = (float*)d_out;
    const size_t e_bytes = (size_t)NB * NN * ND * sizeof(float);   // 1 MB

    dim3 grid(NB * (NN / NWAVES));   // 1024 workgroups
    dim3 block(256);

    if (ws_size >= e_bytes) {
        float* E = (float*)d_ws;
        prep_kernel<<<dim3(NB * NN * ND / 4 / 256), dim3(256), 0, stream>>>(x, E);
        addattn_kernel<true><<<grid, block, 0, stream>>>(x, E, out);
    } else {
        addattn_kernel<false><<<grid, block, 0, stream>>>(x, (const float*)nullptr, out);
    }
}

// Round 3
// 70.924 us; speedup vs baseline: 1.5062x; 1.0572x over previous
//
#include <hip/hip_runtime.h>

// AdditiveSelfAttentionLayer: B=4, N=1024, D=64, fp32
// out[b,i,d] = sum_j softmax_j( sum_d' tanh(x[b,i,d']+x[b,j,d']) ) * x[b,j,d]
//
// Identities:
//   tanh(s) = 1 - 2/(1+e^{2s});  e_j = sum_d tanh = 64 - 2*rsum
//   e^{2s} = E_i[d]*E_j[d],  E = exp2(C*x), C = 2*log2(e)   (precomputed once)
//   softmax shift 32: w_j = exp(e_j - 32) = exp2(32*log2e - C*rsum_j)

#define NB 4
#define NN 1024
#define ND 64
#define TJ 64             // j-rows per LDS tile (lane = local j)
#define TI 8              // i-rows per WG
#define IPW 2             // i-rows per wave
#define NTILES (NN / TJ)  // 16

#if __has_builtin(__builtin_amdgcn_exp2f)
#define EXP2F(x) __builtin_amdgcn_exp2f(x)
#else
#define EXP2F(x) exp2f(x)
#endif
#if __has_builtin(__builtin_amdgcn_rcpf)
#define RCPF(x) __builtin_amdgcn_rcpf(x)
#else
#define RCPF(x) (1.0f / (x))
#endif

static constexpr float C_SCALE = 2.8853900817779268f;   // 2*log2(e)
static constexpr float K_SHIFT = 46.166241308446828f;   // 32*log2(e)

// prep: E[i] = exp2(C * x[i]) for all B*N*D elements
__global__ __launch_bounds__(256) void prep_kernel(const float* __restrict__ x,
                                                   float* __restrict__ E) {
    int idx = blockIdx.x * 256 + threadIdx.x;
    float4 v = ((const float4*)x)[idx];
    float4 e;
    e.x = EXP2F(C_SCALE * v.x);
    e.y = EXP2F(C_SCALE * v.y);
    e.z = EXP2F(C_SCALE * v.z);
    e.w = EXP2F(C_SCALE * v.w);
    ((float4*)E)[idx] = e;
}

template <bool HAS_E>
__global__ __launch_bounds__(256) void addattn_kernel(const float* __restrict__ x,
                                                      const float* __restrict__ E,
                                                      float* __restrict__ out) {
    __shared__ float E_lds[TJ * ND];        // 16 KB, XOR-swizzled at float4 grain
    __shared__ float x_lds[TJ * ND];        // 16 KB, linear (PV reads coalesced)
    __shared__ float Ei_lds[TI * ND];       // 2 KB
    __shared__ float w_lds[4 * IPW * ND];   // 2 KB, per-wave private rows

    const int tid   = threadIdx.x;
    const int lane  = tid & 63;
    const int wave  = tid >> 6;
    const int wg    = blockIdx.x;
    const int b     = wg >> 7;              // 128 WGs per batch
    const int ibase = (wg & 127) * TI;

    const float* xb = x + (size_t)b * NN * ND;
    const float* Eb = E + (size_t)b * NN * ND;

    // stage E for this WG's TI i-rows (contiguous TI*ND floats)
    if (tid < TI * ND / 4) {
        if (HAS_E) {
            ((float4*)Ei_lds)[tid] = ((const float4*)(Eb + (size_t)ibase * ND))[tid];
        } else {
            float4 v = ((const float4*)(xb + (size_t)ibase * ND))[tid];
            float4 e;
            e.x = EXP2F(C_SCALE * v.x);
            e.y = EXP2F(C_SCALE * v.y);
            e.z = EXP2F(C_SCALE * v.z);
            e.w = EXP2F(C_SCALE * v.w);
            ((float4*)Ei_lds)[tid] = e;
        }
    }

    float acc0a = 0.f, acc0b = 0.f, acc1a = 0.f, acc1b = 0.f;  // out numerators, d=lane
    float dn0 = 0.f, dn1 = 0.f;                                // per-lane denom partials

    for (int t = 0; t < NTILES; ++t) {
        __syncthreads();   // protect LDS from previous tile's readers (publishes Ei at t=0)
        {
            const float4* srcx = (const float4*)(xb + (size_t)t * TJ * ND);
            const float4* srcE = (const float4*)(Eb + (size_t)t * TJ * ND);
            #pragma unroll
            for (int it = 0; it < (TJ * ND / 4) / 256; ++it) {   // 4 iters
                int idx = it * 256 + tid;
                int j   = idx >> 4;         // 16 float4 per row
                int c   = idx & 15;
                float4 xv = srcx[idx];
                ((float4*)x_lds)[idx] = xv;              // linear
                float4 ev;
                if (HAS_E) {
                    ev = srcE[idx];
                } else {
                    ev.x = EXP2F(C_SCALE * xv.x);
                    ev.y = EXP2F(C_SCALE * xv.y);
                    ev.z = EXP2F(C_SCALE * xv.z);
                    ev.w = EXP2F(C_SCALE * xv.w);
                }
                *(float4*)&E_lds[j * ND + ((c ^ (j & 15)) << 2)] = ev;  // swizzled
            }
        }
        __syncthreads();

        // ---- tanh phase: lane = local j; 2 i-rows per wave ----
        const int xorkey = lane & 15;
        const float* Ei0 = &Ei_lds[(wave * IPW + 0) * ND];
        const float* Ei1 = &Ei_lds[(wave * IPW + 1) * ND];
        float4 rs0 = {0.f, 0.f, 0.f, 0.f};
        float4 rs1 = {0.f, 0.f, 0.f, 0.f};
        #pragma unroll
        for (int c = 0; c < 16; ++c) {
            float4 ej = *(const float4*)&E_lds[lane * ND + ((c ^ xorkey) << 2)];
            float4 e0 = *(const float4*)&Ei0[c * 4];    // same-addr broadcast
            float4 e1 = *(const float4*)&Ei1[c * 4];
            rs0.x += RCPF(fmaf(e0.x, ej.x, 1.0f));
            rs0.y += RCPF(fmaf(e0.y, ej.y, 1.0f));
            rs0.z += RCPF(fmaf(e0.z, ej.z, 1.0f));
            rs0.w += RCPF(fmaf(e0.w, ej.w, 1.0f));
            rs1.x += RCPF(fmaf(e1.x, ej.x, 1.0f));
            rs1.y += RCPF(fmaf(e1.y, ej.y, 1.0f));
            rs1.z += RCPF(fmaf(e1.z, ej.z, 1.0f));
            rs1.w += RCPF(fmaf(e1.w, ej.w, 1.0f));
        }
        float r0 = (rs0.x + rs0.y) + (rs0.z + rs0.w);
        float r1 = (rs1.x + rs1.y) + (rs1.z + rs1.w);
        float w0 = EXP2F(fmaf(-C_SCALE, r0, K_SHIFT));  // = exp(e_j - 32), <= ~e^-7
        float w1 = EXP2F(fmaf(-C_SCALE, r1, K_SHIFT));
        dn0 += w0;
        dn1 += w1;

        // publish w to this wave's private LDS rows (same-wave round trip; no barrier)
        w_lds[(wave * IPW + 0) * ND + lane] = w0;
        w_lds[(wave * IPW + 1) * ND + lane] = w1;

        // ---- PV phase: acc[i, d=lane] += sum_j w_ij * x[j][lane] ----
        // w via b128 broadcast; x reads shared across both i's; 2 acc chains per i.
        #pragma unroll
        for (int j8 = 0; j8 < 8; ++j8) {
            {
                const int j4 = j8 * 2;
                float4 wq0 = *(const float4*)&w_lds[(wave * IPW + 0) * ND + j4 * 4];
                float4 wq1 = *(const float4*)&w_lds[(wave * IPW + 1) * ND + j4 * 4];
                float xv0 = x_lds[(j4 * 4 + 0) * ND + lane];
                float xv1 = x_lds[(j4 * 4 + 1) * ND + lane];
                float xv2 = x_lds[(j4 * 4 + 2) * ND + lane];
                float xv3 = x_lds[(j4 * 4 + 3) * ND + lane];
                acc0a = fmaf(wq0.x, xv0, acc0a);
                acc0a = fmaf(wq0.y, xv1, acc0a);
                acc0a = fmaf(wq0.z, xv2, acc0a);
                acc0a = fmaf(wq0.w, xv3, acc0a);
                acc1a = fmaf(wq1.x, xv0, acc1a);
                acc1a = fmaf(wq1.y, xv1, acc1a);
                acc1a = fmaf(wq1.z, xv2, acc1a);
                acc1a = fmaf(wq1.w, xv3, acc1a);
            }
            {
                const int j4 = j8 * 2 + 1;
                float4 wq0 = *(const float4*)&w_lds[(wave * IPW + 0) * ND + j4 * 4];
                float4 wq1 = *(const float4*)&w_lds[(wave * IPW + 1) * ND + j4 * 4];
                float xv0 = x_lds[(j4 * 4 + 0) * ND + lane];
                float xv1 = x_lds[(j4 * 4 + 1) * ND + lane];
                float xv2 = x_lds[(j4 * 4 + 2) * ND + lane];
                float xv3 = x_lds[(j4 * 4 + 3) * ND + lane];
                acc0b = fmaf(wq0.x, xv0, acc0b);
                acc0b = fmaf(wq0.y, xv1, acc0b);
                acc0b = fmaf(wq0.z, xv2, acc0b);
                acc0b = fmaf(wq0.w, xv3, acc0b);
                acc1b = fmaf(wq1.x, xv0, acc1b);
                acc1b = fmaf(wq1.y, xv1, acc1b);
                acc1b = fmaf(wq1.z, xv2, acc1b);
                acc1b = fmaf(wq1.w, xv3, acc1b);
            }
        }
    }

    // reduce denominators across lanes (each lane held w for its j's)
    #pragma unroll
    for (int s = 0; s < 6; ++s) {
        dn0 += __shfl_xor(dn0, 1 << s, 64);
        dn1 += __shfl_xor(dn1, 1 << s, 64);
    }

    const int i0 = ibase + wave * IPW;
    out[((size_t)b * NN + i0) * ND + lane]     = (acc0a + acc0b) * RCPF(dn0);
    out[((size_t)b * NN + i0 + 1) * ND + lane] = (acc1a + acc1b) * RCPF(dn1);
}

extern "C" void kernel_launch(void* const* d_in, const int* in_sizes, int n_in,
                              void* d_out, int out_size, void* d_ws, size_t ws_size,
                              hipStream_t stream) {
    const float* x = (const float*)d_in[0];
    float* out = (float*)d_out;
    const size_t e_bytes = (size_t)NB * NN * ND * sizeof(float);   // 1 MB

    dim3 grid(NB * (NN / TI));   // 512 workgroups
    dim3 block(256);

    if (ws_size >= e_bytes) {
        float* E = (float*)d_ws;
        prep_kernel<<<dim3(NB * NN * ND / 4 / 256), dim3(256), 0, stream>>>(x, E);
        addattn_kernel<true><<<grid, block, 0, stream>>>(x, E, out);
    } else {
        addattn_kernel<false><<<grid, block, 0, stream>>>(x, (const float*)nullptr, out);
    }
}